// Round 6
// baseline (451.860 us; speedup 1.0000x reference)
//
#include <hip/hip_runtime.h>
#include <hip/hip_bf16.h>
#include <math.h>

#define B 8
#define C 512
#define L 2048

using bf16x8 = __bf16 __attribute__((ext_vector_type(8)));
using f32x4  = float __attribute__((ext_vector_type(4)));

#define MFMA(a, b, c) __builtin_amdgcn_mfma_f32_16x16x32_bf16((a), (b), (c), 0, 0, 0)
// exp(v*SCALE - 12) == exp2(v*SC2 + SH2), SCALE = 1/sqrt(512)
#define SC2 0.06375872f
#define SH2 -17.312340f

// grid-barrier counter: lives in a device global so it aliases no workspace
// buffer; re-zeroed by qkv_gemm every launch (kernel boundary orders it
// before sc_pv). Cross-XCD coherence via device-scope atomics (G12/m20).
__device__ unsigned g_ctr;

// RNE f32->bf16 without NaN handling (all values here are finite)
__device__ __forceinline__ unsigned short f2bf(float f) {
    unsigned int u; __builtin_memcpy(&u, &f, 4);
    u += 0x7FFF + ((u >> 16) & 1);
    return (unsigned short)(u >> 16);
}
// async global->LDS, 16B/lane; LDS dest = wave-uniform base + lane*16
__device__ __forceinline__ void load_lds16(const unsigned short* g, unsigned short* l) {
    __builtin_amdgcn_global_load_lds(
        (const __attribute__((address_space(1))) unsigned int*)g,
        (__attribute__((address_space(3))) unsigned int*)l, 16, 0, 0);
}

// ---------------------------------------------------------------------------
// GEMM-NT core (legacy 128x128, 2-barrier): used by qkv_gemm (+ fallback pv).
// MODE 0: +bias[col], bf16 out      (QKV q/k)
// MODE 1: +bias[row], bf16 out      (QKV v)
// MODE 3: /ep[col], f32 out         (PV, ep = row sums)
// ---------------------------------------------------------------------------
template<int MODE, int KDIM>
__device__ __forceinline__ void gemm_core(
    const unsigned short* __restrict__ A,   // pre-offset to tile row m0
    const unsigned short* __restrict__ Bm,  // pre-offset to tile row n0
    unsigned short* As, unsigned short* Bs, // [2][128*32] each
    void* __restrict__ OutV, int ldo,       // pre-offset to (m0, n0)
    float* __restrict__ ep)                 // bias / rsum (pre-offset)
{
    const int t = threadIdx.x;
    const int wave = t >> 6, lane = t & 63;
    const int ll = t & 15, quad = (t >> 4) & 3;
    const int lr = lane >> 2, chunk = lane & 3;
    const int wm = (wave & 1) * 64, wn = (wave >> 1) * 64;

    const unsigned short* gA0 = A  + (size_t)(wave * 32 + lr) * KDIM + chunk * 8;
    const unsigned short* gB0 = Bm + (size_t)(wave * 32 + lr) * KDIM + chunk * 8;
    unsigned short* lA0 = As + (wave * 32) * 32;        // wave-uniform bases
    unsigned short* lB0 = Bs + (wave * 32) * 32;
    const int P1 = 128 * 32;                            // panel-1 offset

    f32x4 acc[4][4];
#pragma unroll
    for (int i = 0; i < 4; ++i)
#pragma unroll
        for (int j = 0; j < 4; ++j) acc[i][j] = (f32x4){0.f, 0.f, 0.f, 0.f};

#pragma unroll 1
    for (int k0 = 0; k0 < KDIM; k0 += 64) {
        __syncthreads();                      // prev compute done reading LDS
        load_lds16(gA0 + k0, lA0);
        load_lds16(gA0 + (size_t)16 * KDIM + k0, lA0 + 16 * 32);
        load_lds16(gA0 + k0 + 32, lA0 + P1);
        load_lds16(gA0 + (size_t)16 * KDIM + k0 + 32, lA0 + P1 + 16 * 32);
        load_lds16(gB0 + k0, lB0);
        load_lds16(gB0 + (size_t)16 * KDIM + k0, lB0 + 16 * 32);
        load_lds16(gB0 + k0 + 32, lB0 + P1);
        load_lds16(gB0 + (size_t)16 * KDIM + k0 + 32, lB0 + P1 + 16 * 32);
        __syncthreads();                      // staging visible

#pragma unroll
        for (int p = 0; p < 2; ++p) {
            bf16x8 af[4], bf[4];
#pragma unroll
            for (int mi = 0; mi < 4; ++mi)
                af[mi] = *(const bf16x8*)&As[p * P1 + (wm + mi * 16 + ll) * 32 + quad * 8];
#pragma unroll
            for (int ni = 0; ni < 4; ++ni)
                bf[ni] = *(const bf16x8*)&Bs[p * P1 + (wn + ni * 16 + ll) * 32 + quad * 8];
#pragma unroll
            for (int mi = 0; mi < 4; ++mi)
#pragma unroll
                for (int ni = 0; ni < 4; ++ni)
                    acc[mi][ni] = MFMA(af[mi], bf[ni], acc[mi][ni]);
        }
    }

#pragma unroll
    for (int mi = 0; mi < 4; ++mi)
#pragma unroll
        for (int ni = 0; ni < 4; ++ni) {
            const int col = wn + ni * 16 + ll;
            float epc = 0.f;
            if (MODE == 0) epc = ep[col];
            if (MODE == 3) epc = 1.0f / ep[col];
#pragma unroll
            for (int r = 0; r < 4; ++r) {
                const int row = wm + mi * 16 + quad * 4 + r;
                float v = acc[mi][ni][r];
                if (MODE == 0)      v += epc;
                else if (MODE == 1) v += ep[row];
                else                v *= epc;
                if (MODE == 3)
                    ((float*)OutV)[(size_t)row * ldo + col] = v;
                else
                    ((unsigned short*)OutV)[(size_t)row * ldo + col] = f2bf(v);
            }
        }
}

// ---------------------------------------------------------------------------
// Kernel 0 (merged): x transpose/cvt + W cvt + rsum zero. Grid dim3(32,8,8);
// flat block id < 768 additionally does the old wcvt block's work.
// ---------------------------------------------------------------------------
__global__ __launch_bounds__(256) void prep(
    const float* __restrict__ x, const float* __restrict__ Wq,
    const float* __restrict__ Wk, const float* __restrict__ Wv,
    unsigned short* __restrict__ xt, unsigned short* __restrict__ o,
    float* __restrict__ rsum)
{
    __shared__ float tile[64][69];
    const int t = threadIdx.x;
    const int flat = blockIdx.x + 32 * (blockIdx.y + 8 * blockIdx.z);

    if (flat < 768) {               // ---- wcvt part (independent data) ----
        if (flat < 16) {            // zero rsum[B*L] = 16384 floats
            float4 z = make_float4(0.f, 0.f, 0.f, 0.f);
            *(float4*)(rsum + (flat * 256 + t) * 4) = z;
        }
        const int i = (flat * 256 + t) * 4;
        const int which = i >> 18;                            // C*C = 2^18
        const int off = i & 0x3FFFF;
        const float* src = (which == 0) ? Wq : (which == 1) ? Wk : Wv;
        float4 v = *(const float4*)(src + off);
        union { unsigned short h[4]; uint2 u; } pk;
        pk.h[0] = f2bf(v.x); pk.h[1] = f2bf(v.y); pk.h[2] = f2bf(v.z); pk.h[3] = f2bf(v.w);
        *(uint2*)(o + i) = pk.u;
    }

    // ---- xpose part ----
    const int b = blockIdx.z, l0 = blockIdx.x * 64, c0 = blockIdx.y * 64;
    const int lx = t & 15, cy = t >> 4;          // load: float4 along L
    const float* xb = x + (size_t)b * C * L;
#pragma unroll
    for (int p = 0; p < 4; ++p) {
        float4 v = *(const float4*)(xb + (size_t)(c0 + p * 16 + cy) * L + l0 + lx * 4);
        tile[p * 16 + cy][lx * 4 + 0] = v.x;
        tile[p * 16 + cy][lx * 4 + 1] = v.y;
        tile[p * 16 + cy][lx * 4 + 2] = v.z;
        tile[p * 16 + cy][lx * 4 + 3] = v.w;
    }
    __syncthreads();
    const int ocl = t & 15, ot = t >> 4;         // store: 4 bf16 (8B) along C
    unsigned short* xtb = xt + (size_t)b * L * C;
#pragma unroll
    for (int p = 0; p < 4; ++p) {
        int ol = p * 16 + ot;
        union { unsigned short h[4]; uint2 u; } pk;
#pragma unroll
        for (int i = 0; i < 4; ++i) pk.h[i] = f2bf(tile[ocl * 4 + i][ol]);
        *(uint2*)(xtb + (size_t)(l0 + ol) * C + c0 + ocl * 4) = pk.u;
    }
}

// ---------------------------------------------------------------------------
// Kernel 1: QKV projection. 1-D grid 1536: b = id&7 (XCD), r = id>>3:
//   which = r>>6; q/k: m = tt&15 (fastest), n = tt>>4; v: m = tt&3, n = tt>>2
// Also re-zeroes the sc_pv grid-barrier counter (kernel boundary orders it).
// ---------------------------------------------------------------------------
__global__ __launch_bounds__(256) void qkv_gemm(
    const unsigned short* __restrict__ xt, const unsigned short* __restrict__ Wb,
    const float* __restrict__ bq, const float* __restrict__ bk,
    const float* __restrict__ bv,
    unsigned short* __restrict__ Qt, unsigned short* __restrict__ Kt,
    unsigned short* __restrict__ Vv)
{
    __shared__ unsigned short As[2 * 128 * 32], Bs[2 * 128 * 32];
    if (blockIdx.x == 0 && threadIdx.x == 0)
        __hip_atomic_store(&g_ctr, 0u, __ATOMIC_RELAXED, __HIP_MEMORY_SCOPE_AGENT);
    const int id = blockIdx.x;
    const int b = id & 7, r = id >> 3;          // r in 0..191
    const int which = r >> 6, tt = r & 63;
    const unsigned short* xtb = xt + (size_t)b * L * C;
    if (which < 2) {
        const int m0 = (tt & 15) * 128, n0 = (tt >> 4) * 128;   // M=L, N=C
        const unsigned short* A  = xtb + (size_t)m0 * C;
        const unsigned short* Bm = Wb + (size_t)which * C * C + (size_t)n0 * C;
        unsigned short* Out = (which ? Kt : Qt) + (size_t)b * L * C
                              + (size_t)m0 * C + n0;
        gemm_core<0, C>(A, Bm, As, Bs, Out, C,
                        const_cast<float*>((which ? bk : bq) + n0));
    } else {
        const int m0 = (tt & 3) * 128, n0 = (tt >> 2) * 128;    // M=C, N=L
        const unsigned short* A  = Wb + (size_t)2 * C * C + (size_t)m0 * C;
        const unsigned short* Bm = xtb + (size_t)n0 * C;
        unsigned short* Out = Vv + (size_t)b * C * L + (size_t)m0 * L + n0;
        gemm_core<1, C>(A, Bm, As, Bs, Out, L, const_cast<float*>(bv + m0));
    }
}

// ---------------------------------------------------------------------------
// Kernel 2 (fused, fullP path): P = exp(QK^T*scale-12) + rsum, grid barrier,
// then O = (V @ P^T)/rsum. 512 blocks x 512 thr, 48 KiB LDS static.
// Residency proof (no-deadlock): launch_bounds(512,4) caps VGPR at 128 ->
// >=2 blocks/CU by VGPR; LDS 2x48=96<=160; waves 16<=32; 256 CU x 2 = 512
// blocks all co-resident, so the software grid barrier always completes.
// P/rsum producers & consumers share b = id&7 -> same XCD -> same L2;
// __threadfence release/acquire around the barrier handles L1/L2 coherence.
// Phase 1: per block 2 sc-tiles (256x128, BK=64, swizzled staging; same core
//          as R5's sc_exp3, proven correct/56 VGPR).
// Phase 2: pv tile 128x128, K=2048, 8 waves (2M x 4N of 64x32), swizzled
//          staging (removes old pv_gemm's 4.2M bank conflicts).
// ---------------------------------------------------------------------------
__global__ __launch_bounds__(512, 4) void sc_pv(
    const unsigned short* __restrict__ Qt, const unsigned short* __restrict__ Kt,
    const unsigned short* __restrict__ Vv, unsigned short* __restrict__ P,
    float* __restrict__ rsum, float* __restrict__ out)
{
    __shared__ unsigned short As[256 * 64];   // 32 KiB
    __shared__ unsigned short Bs[128 * 64];   // 16 KiB

    const int id = blockIdx.x;
    const int b = id & 7, rr = id >> 3;       // rr in 0..63
    const int t = threadIdx.x;
    const int wave = t >> 6;
    const int ll = t & 15, quad = (t >> 4) & 3;
    const int r0 = t >> 3;                    // staging row within 64-row group
    const int swz = ((t & 7) ^ (r0 & 7)) * 8; // inverse-swizzled global chunk
    const int sw8 = ll & 7;                   // read-side swizzle key

    // ================= phase 1: two 256x128 P-tiles + rsum =================
    {
        const int n0 = (rr & 15) * 128, mp = rr >> 4;        // 16 n x 4 mp
        const unsigned short* gB = Kt + (size_t)b * L * C
                                   + (size_t)(n0 + r0) * C + swz;
        const int wm = (wave & 3) * 64, wn = (wave >> 2) * 64;  // 4M x 2N
        unsigned short* lA = As + wave * 512;
        unsigned short* lB = Bs + wave * 512;

#pragma unroll 1
        for (int s = 0; s < 2; ++s) {
            const int m0 = (mp * 2 + s) * 256;
            const unsigned short* gA = Qt + (size_t)b * L * C
                                       + (size_t)(m0 + r0) * C + swz;
            unsigned short* Out = P + (size_t)b * L * L + (size_t)m0 * L + n0;
            float* ep = rsum + (size_t)b * L + m0;

            f32x4 acc[4][4];
#pragma unroll
            for (int i = 0; i < 4; ++i)
#pragma unroll
                for (int j = 0; j < 4; ++j) acc[i][j] = (f32x4){0.f, 0.f, 0.f, 0.f};

#pragma unroll 1
            for (int k0 = 0; k0 < C; k0 += 64) {
                __syncthreads();
                load_lds16(gA + k0,                    lA);
                load_lds16(gA + (size_t)64  * C + k0,  lA + 64 * 64);
                load_lds16(gA + (size_t)128 * C + k0,  lA + 128 * 64);
                load_lds16(gA + (size_t)192 * C + k0,  lA + 192 * 64);
                load_lds16(gB + k0,                    lB);
                load_lds16(gB + (size_t)64  * C + k0,  lB + 64 * 64);
                __syncthreads();
#pragma unroll
                for (int p = 0; p < 2; ++p) {
                    bf16x8 af[4], bf[4];
#pragma unroll
                    for (int mi = 0; mi < 4; ++mi)
                        af[mi] = *(const bf16x8*)&As[(wm + mi * 16 + ll) * 64
                                                     + ((p * 4 + quad) ^ sw8) * 8];
#pragma unroll
                    for (int ni = 0; ni < 4; ++ni)
                        bf[ni] = *(const bf16x8*)&Bs[(wn + ni * 16 + ll) * 64
                                                     + ((p * 4 + quad) ^ sw8) * 8];
#pragma unroll
                    for (int mi = 0; mi < 4; ++mi)
#pragma unroll
                        for (int ni = 0; ni < 4; ++ni)
                            acc[mi][ni] = MFMA(af[mi], bf[ni], acc[mi][ni]);
                }
            }

            float rpart[4][4];
#pragma unroll
            for (int mi = 0; mi < 4; ++mi)
#pragma unroll
                for (int r = 0; r < 4; ++r) rpart[mi][r] = 0.f;
#pragma unroll
            for (int mi = 0; mi < 4; ++mi)
#pragma unroll
                for (int ni = 0; ni < 4; ++ni) {
                    const int col = wn + ni * 16 + ll;
#pragma unroll
                    for (int r = 0; r < 4; ++r) {
                        const int row = wm + mi * 16 + quad * 4 + r;
                        float v = exp2f(fmaf(acc[mi][ni][r], SC2, SH2));
                        rpart[mi][r] += v;
                        Out[(size_t)row * L + col] = f2bf(v);
                    }
                }
#pragma unroll
            for (int mi = 0; mi < 4; ++mi)
#pragma unroll
                for (int r = 0; r < 4; ++r) {
                    float s2 = rpart[mi][r];
                    s2 += __shfl_xor(s2, 1, 64);
                    s2 += __shfl_xor(s2, 2, 64);
                    s2 += __shfl_xor(s2, 4, 64);
                    s2 += __shfl_xor(s2, 8, 64);
                    if (ll == 0) atomicAdd(ep + wm + mi * 16 + quad * 4 + r, s2);
                }
        }
    }

    // ========================= grid barrier =========================
    __syncthreads();           // all waves' P stores drained (vmcnt=0 at bar)
    __threadfence();           // release to device scope
    if (t == 0) {
        atomicAdd(&g_ctr, 1u); // device-scope
        while (__hip_atomic_load(&g_ctr, __ATOMIC_RELAXED,
                                 __HIP_MEMORY_SCOPE_AGENT) < 512u)
            __builtin_amdgcn_s_sleep(2);
    }
    __syncthreads();
    __threadfence();           // acquire: invalidate L1 before P/rsum reads

    // ============ phase 2: out tile 128x128 = (V @ P^T)/rsum ============
    {
        const int m0 = (rr & 3) * 128, n0 = (rr >> 2) * 128;   // 4m x 16n
        const unsigned short* gA = Vv + (size_t)b * C * L
                                   + (size_t)(m0 + r0) * L + swz;
        const unsigned short* gB = P + (size_t)b * L * L
                                   + (size_t)(n0 + r0) * L + swz;
        float* Out = out + (size_t)b * C * L + (size_t)m0 * L + n0;
        const float* ep = rsum + (size_t)b * L + n0;
        const int wm = (wave & 1) * 64, wn = (wave >> 1) * 32;  // 2M x 4N
        unsigned short* lAa = As + wave * 512;          // rows 0-63
        unsigned short* lAb = As + 4096 + wave * 512;   // rows 64-127
        unsigned short* lBa = Bs + wave * 512;
        unsigned short* lBb = Bs + 4096 + wave * 512;

        f32x4 acc[4][2];
#pragma unroll
        for (int i = 0; i < 4; ++i)
#pragma unroll
            for (int j = 0; j < 2; ++j) acc[i][j] = (f32x4){0.f, 0.f, 0.f, 0.f};

#pragma unroll 1
        for (int k0 = 0; k0 < L; k0 += 64) {
            __syncthreads();
            load_lds16(gA + k0,                   lAa);
            load_lds16(gA + (size_t)64 * L + k0,  lAb);
            load_lds16(gB + k0,                   lBa);
            load_lds16(gB + (size_t)64 * L + k0,  lBb);
            __syncthreads();
#pragma unroll
            for (int p = 0; p < 2; ++p) {
                bf16x8 af[4], bf[2];
#pragma unroll
                for (int mi = 0; mi < 4; ++mi)
                    af[mi] = *(const bf16x8*)&As[(wm + mi * 16 + ll) * 64
                                                 + ((p * 4 + quad) ^ sw8) * 8];
#pragma unroll
                for (int ni = 0; ni < 2; ++ni)
                    bf[ni] = *(const bf16x8*)&Bs[(wn + ni * 16 + ll) * 64
                                                 + ((p * 4 + quad) ^ sw8) * 8];
#pragma unroll
                for (int mi = 0; mi < 4; ++mi)
#pragma unroll
                    for (int ni = 0; ni < 2; ++ni)
                        acc[mi][ni] = MFMA(af[mi], bf[ni], acc[mi][ni]);
            }
        }

#pragma unroll
        for (int mi = 0; mi < 4; ++mi)
#pragma unroll
            for (int ni = 0; ni < 2; ++ni) {
                const int col = wn + ni * 16 + ll;
                const float inv = 1.0f / ep[col];
#pragma unroll
                for (int r = 0; r < 4; ++r) {
                    const int row = wm + mi * 16 + quad * 4 + r;
                    Out[(size_t)row * L + col] = acc[mi][ni][r] * inv;
                }
            }
    }
}

// ---------------------------------------------------------------------------
// Fallback kernels (ws too small for full P): R5's sc_exp3 + pv_gemm
// ---------------------------------------------------------------------------
__global__ __launch_bounds__(512, 4) void sc_exp3(
    const unsigned short* __restrict__ Qt, const unsigned short* __restrict__ Kt,
    unsigned short* __restrict__ P, float* __restrict__ rsum,
    int hoff, int qrows, int mshift)
{
    __shared__ unsigned short As[256 * 64];
    __shared__ unsigned short Bs[128 * 64];
    constexpr int KD = C;

    const int id = blockIdx.x;
    const int b = id & 7, rr = id >> 3;
    const int m0 = (rr & ((1 << mshift) - 1)) * 256, n0 = (rr >> mshift) * 128;
    const unsigned short* A  = Qt + (size_t)b * L * C + (size_t)(hoff + m0) * C;
    const unsigned short* Bm = Kt + (size_t)b * L * C + (size_t)n0 * C;
    unsigned short* Out = P + (size_t)b * qrows * L + (size_t)m0 * L + n0;
    float* ep = rsum + (size_t)b * L + hoff + m0;

    const int t = threadIdx.x;
    const int wave = t >> 6;
    const int ll = t & 15, quad = (t >> 4) & 3;
    const int wm = (wave & 3) * 64, wn = (wave >> 2) * 64;
    const int r0 = t >> 3;
    const int swz = ((t & 7) ^ (r0 & 7)) * 8;
    const unsigned short* gA = A  + (size_t)r0 * KD + swz;
    const unsigned short* gB = Bm + (size_t)r0 * KD + swz;
    unsigned short* lA = As + wave * 512;
    unsigned short* lB = Bs + wave * 512;
    const int sw8 = ll & 7;

    f32x4 acc[4][4];
#pragma unroll
    for (int i = 0; i < 4; ++i)
#pragma unroll
        for (int j = 0; j < 4; ++j) acc[i][j] = (f32x4){0.f, 0.f, 0.f, 0.f};

#pragma unroll 1
    for (int k0 = 0; k0 < KD; k0 += 64) {
        __syncthreads();
        load_lds16(gA + k0,                     lA);
        load_lds16(gA + (size_t)64  * KD + k0,  lA + 64 * 64);
        load_lds16(gA + (size_t)128 * KD + k0,  lA + 128 * 64);
        load_lds16(gA + (size_t)192 * KD + k0,  lA + 192 * 64);
        load_lds16(gB + k0,                     lB);
        load_lds16(gB + (size_t)64  * KD + k0,  lB + 64 * 64);
        __syncthreads();
#pragma unroll
        for (int p = 0; p < 2; ++p) {
            bf16x8 af[4], bf[4];
#pragma unroll
            for (int mi = 0; mi < 4; ++mi)
                af[mi] = *(const bf16x8*)&As[(wm + mi * 16 + ll) * 64
                                             + ((p * 4 + quad) ^ sw8) * 8];
#pragma unroll
            for (int ni = 0; ni < 4; ++ni)
                bf[ni] = *(const bf16x8*)&Bs[(wn + ni * 16 + ll) * 64
                                             + ((p * 4 + quad) ^ sw8) * 8];
#pragma unroll
            for (int mi = 0; mi < 4; ++mi)
#pragma unroll
                for (int ni = 0; ni < 4; ++ni)
                    acc[mi][ni] = MFMA(af[mi], bf[ni], acc[mi][ni]);
        }
    }

    float rpart[4][4];
#pragma unroll
    for (int mi = 0; mi < 4; ++mi)
#pragma unroll
        for (int r = 0; r < 4; ++r) rpart[mi][r] = 0.f;
#pragma unroll
    for (int mi = 0; mi < 4; ++mi)
#pragma unroll
        for (int ni = 0; ni < 4; ++ni) {
            const int col = wn + ni * 16 + ll;
#pragma unroll
            for (int r = 0; r < 4; ++r) {
                const int row = wm + mi * 16 + quad * 4 + r;
                float v = exp2f(fmaf(acc[mi][ni][r], SC2, SH2));
                rpart[mi][r] += v;
                Out[(size_t)row * L + col] = f2bf(v);
            }
        }
#pragma unroll
    for (int mi = 0; mi < 4; ++mi)
#pragma unroll
        for (int r = 0; r < 4; ++r) {
            float s = rpart[mi][r];
            s += __shfl_xor(s, 1, 64);
            s += __shfl_xor(s, 2, 64);
            s += __shfl_xor(s, 4, 64);
            s += __shfl_xor(s, 8, 64);
            if (ll == 0) atomicAdd(ep + wm + mi * 16 + quad * 4 + r, s);
        }
}

__global__ __launch_bounds__(256) void pv_gemm(
    const unsigned short* __restrict__ Vv, const unsigned short* __restrict__ P,
    const float* __restrict__ rsum, float* __restrict__ out,
    int hoff, int qrows)
{
    __shared__ unsigned short As[2 * 128 * 32], Bs[2 * 128 * 32];
    const int id = blockIdx.x;
    const int b = id & 7, r = id >> 3;
    const int m0 = (r & 3) * 128, n0 = (r >> 2) * 128;
    const unsigned short* A  = Vv + (size_t)b * C * L + (size_t)m0 * L;
    const unsigned short* Bm = P + (size_t)b * qrows * L + (size_t)n0 * L;
    float* Out = out + (size_t)b * C * L + (size_t)m0 * L + hoff + n0;
    float* ep = const_cast<float*>(rsum) + (size_t)b * L + hoff + n0;
    gemm_core<3, L>(A, Bm, As, Bs, Out, L, ep);
}

extern "C" void kernel_launch(void* const* d_in, const int* in_sizes, int n_in,
                              void* d_out, int out_size, void* d_ws, size_t ws_size,
                              hipStream_t stream) {
    const float* x  = (const float*)d_in[0];
    const float* Wq = (const float*)d_in[1];
    const float* bq = (const float*)d_in[2];
    const float* Wk = (const float*)d_in[3];
    const float* bk = (const float*)d_in[4];
    const float* Wv = (const float*)d_in[5];
    const float* bv = (const float*)d_in[6];
    float* out = (float*)d_out;

    const size_t BCL = (size_t)B * C * L;                // 8.39M elems
    const bool fullP = ws_size >= 119078912ull;          // full-P footprint

    unsigned short* Qt = (unsigned short*)d_ws;          // [B][L][C] bf16
    unsigned short* Kt = Qt + BCL;
    unsigned short* Vv = Kt + BCL;                       // [B][C][L]
    unsigned short *Wb, *xt, *P;
    float* rsum;
    if (fullP) {
        Wb   = Vv + BCL;                                 // 1.57 MB, live during qkv
        rsum = (float*)(Wb + (size_t)3 * C * C);         // [B][L] f32
        xt   = (unsigned short*)(rsum + (size_t)B * L);  // dead after qkv
        P    = xt;                                       // [B][L][L] bf16, aliases xt
    } else {                                             // 85.6 MB fallback
        xt   = Vv + BCL;
        P    = xt;                                       // [B][1024][L], aliases xt
        Wb   = P + (size_t)B * 1024 * L;
        rsum = (float*)(Wb + (size_t)3 * C * C);
    }

    prep<<<dim3(L / 64, C / 64, B), 256, 0, stream>>>(x, Wq, Wk, Wv, xt, Wb, rsum);
    qkv_gemm<<<dim3(1536), 256, 0, stream>>>(xt, Wb, bq, bk, bv, Qt, Kt, Vv);

    if (fullP) {
        sc_pv<<<dim3(512), 512, 0, stream>>>(Qt, Kt, Vv, P, rsum, out);
    } else {
        for (int h = 0; h < 2; ++h) {
            sc_exp3<<<dim3(512), 512, 0, stream>>>(Qt, Kt, P, rsum, h * 1024, 1024, 2);
            pv_gemm<<<dim3(256), 256, 0, stream>>>(Vv, P, rsum, out, h * 1024, 1024);
        }
    }
}

// Round 7
// 232.977 us; speedup vs baseline: 1.9395x; 1.9395x over previous
//
#include <hip/hip_runtime.h>
#include <hip/hip_bf16.h>
#include <math.h>

#define B 8
#define C 512
#define L 2048

using bf16x8 = __bf16 __attribute__((ext_vector_type(8)));
using f32x4  = float __attribute__((ext_vector_type(4)));

#define MFMA(a, b, c) __builtin_amdgcn_mfma_f32_16x16x32_bf16((a), (b), (c), 0, 0, 0)
// exp(v*SCALE - 12) == exp2(v*SC2 + SH2), SCALE = 1/sqrt(512)
#define SC2 0.06375872f
#define SH2 -17.312340f

// RNE f32->bf16 without NaN handling (all values here are finite)
__device__ __forceinline__ unsigned short f2bf(float f) {
    unsigned int u; __builtin_memcpy(&u, &f, 4);
    u += 0x7FFF + ((u >> 16) & 1);
    return (unsigned short)(u >> 16);
}
// async global->LDS, 16B/lane; LDS dest = wave-uniform base + lane*16
__device__ __forceinline__ void load_lds16(const unsigned short* g, unsigned short* l) {
    __builtin_amdgcn_global_load_lds(
        (const __attribute__((address_space(1))) unsigned int*)g,
        (__attribute__((address_space(3))) unsigned int*)l, 16, 0, 0);
}

// ---------------------------------------------------------------------------
// GEMM-NT core (legacy 128x128, 2-barrier): used by qkv_gemm / pv_gemm.
// MODE 0: +bias[col], bf16 out      (QKV q/k)
// MODE 1: +bias[row], bf16 out      (QKV v)
// MODE 3: /ep[col], f32 out         (PV, ep = row sums)
// ---------------------------------------------------------------------------
template<int MODE, int KDIM>
__device__ __forceinline__ void gemm_core(
    const unsigned short* __restrict__ A,   // pre-offset to tile row m0
    const unsigned short* __restrict__ Bm,  // pre-offset to tile row n0
    unsigned short* As, unsigned short* Bs, // [2][128*32] each
    void* __restrict__ OutV, int ldo,       // pre-offset to (m0, n0)
    float* __restrict__ ep)                 // bias / rsum (pre-offset)
{
    const int t = threadIdx.x;
    const int wave = t >> 6, lane = t & 63;
    const int ll = t & 15, quad = (t >> 4) & 3;
    const int lr = lane >> 2, chunk = lane & 3;
    const int wm = (wave & 1) * 64, wn = (wave >> 1) * 64;

    const unsigned short* gA0 = A  + (size_t)(wave * 32 + lr) * KDIM + chunk * 8;
    const unsigned short* gB0 = Bm + (size_t)(wave * 32 + lr) * KDIM + chunk * 8;
    unsigned short* lA0 = As + (wave * 32) * 32;        // wave-uniform bases
    unsigned short* lB0 = Bs + (wave * 32) * 32;
    const int P1 = 128 * 32;                            // panel-1 offset

    f32x4 acc[4][4];
#pragma unroll
    for (int i = 0; i < 4; ++i)
#pragma unroll
        for (int j = 0; j < 4; ++j) acc[i][j] = (f32x4){0.f, 0.f, 0.f, 0.f};

#pragma unroll 1
    for (int k0 = 0; k0 < KDIM; k0 += 64) {
        __syncthreads();                      // prev compute done reading LDS
        load_lds16(gA0 + k0, lA0);
        load_lds16(gA0 + (size_t)16 * KDIM + k0, lA0 + 16 * 32);
        load_lds16(gA0 + k0 + 32, lA0 + P1);
        load_lds16(gA0 + (size_t)16 * KDIM + k0 + 32, lA0 + P1 + 16 * 32);
        load_lds16(gB0 + k0, lB0);
        load_lds16(gB0 + (size_t)16 * KDIM + k0, lB0 + 16 * 32);
        load_lds16(gB0 + k0 + 32, lB0 + P1);
        load_lds16(gB0 + (size_t)16 * KDIM + k0 + 32, lB0 + P1 + 16 * 32);
        __syncthreads();                      // staging visible

#pragma unroll
        for (int p = 0; p < 2; ++p) {
            bf16x8 af[4], bf[4];
#pragma unroll
            for (int mi = 0; mi < 4; ++mi)
                af[mi] = *(const bf16x8*)&As[p * P1 + (wm + mi * 16 + ll) * 32 + quad * 8];
#pragma unroll
            for (int ni = 0; ni < 4; ++ni)
                bf[ni] = *(const bf16x8*)&Bs[p * P1 + (wn + ni * 16 + ll) * 32 + quad * 8];
#pragma unroll
            for (int mi = 0; mi < 4; ++mi)
#pragma unroll
                for (int ni = 0; ni < 4; ++ni)
                    acc[mi][ni] = MFMA(af[mi], bf[ni], acc[mi][ni]);
        }
    }

#pragma unroll
    for (int mi = 0; mi < 4; ++mi)
#pragma unroll
        for (int ni = 0; ni < 4; ++ni) {
            const int col = wn + ni * 16 + ll;
            float epc = 0.f;
            if (MODE == 0) epc = ep[col];
            if (MODE == 3) epc = 1.0f / ep[col];
#pragma unroll
            for (int r = 0; r < 4; ++r) {
                const int row = wm + mi * 16 + quad * 4 + r;
                float v = acc[mi][ni][r];
                if (MODE == 0)      v += epc;
                else if (MODE == 1) v += ep[row];
                else                v *= epc;
                if (MODE == 3)
                    ((float*)OutV)[(size_t)row * ldo + col] = v;
                else
                    ((unsigned short*)OutV)[(size_t)row * ldo + col] = f2bf(v);
            }
        }
}

// ---------------------------------------------------------------------------
// Kernel 0 (merged): x transpose/cvt + W cvt + rsum zero. Grid dim3(32,8,8);
// flat block id < 768 additionally does the old wcvt block's work.
// ---------------------------------------------------------------------------
__global__ __launch_bounds__(256) void prep(
    const float* __restrict__ x, const float* __restrict__ Wq,
    const float* __restrict__ Wk, const float* __restrict__ Wv,
    unsigned short* __restrict__ xt, unsigned short* __restrict__ o,
    float* __restrict__ rsum)
{
    __shared__ float tile[64][69];
    const int t = threadIdx.x;
    const int flat = blockIdx.x + 32 * (blockIdx.y + 8 * blockIdx.z);

    if (flat < 768) {               // ---- wcvt part (independent data) ----
        if (flat < 16) {            // zero rsum[B*L] = 16384 floats
            float4 z = make_float4(0.f, 0.f, 0.f, 0.f);
            *(float4*)(rsum + (flat * 256 + t) * 4) = z;
        }
        const int i = (flat * 256 + t) * 4;
        const int which = i >> 18;                            // C*C = 2^18
        const int off = i & 0x3FFFF;
        const float* src = (which == 0) ? Wq : (which == 1) ? Wk : Wv;
        float4 v = *(const float4*)(src + off);
        union { unsigned short h[4]; uint2 u; } pk;
        pk.h[0] = f2bf(v.x); pk.h[1] = f2bf(v.y); pk.h[2] = f2bf(v.z); pk.h[3] = f2bf(v.w);
        *(uint2*)(o + i) = pk.u;
    }

    // ---- xpose part ----
    const int b = blockIdx.z, l0 = blockIdx.x * 64, c0 = blockIdx.y * 64;
    const int lx = t & 15, cy = t >> 4;          // load: float4 along L
    const float* xb = x + (size_t)b * C * L;
#pragma unroll
    for (int p = 0; p < 4; ++p) {
        float4 v = *(const float4*)(xb + (size_t)(c0 + p * 16 + cy) * L + l0 + lx * 4);
        tile[p * 16 + cy][lx * 4 + 0] = v.x;
        tile[p * 16 + cy][lx * 4 + 1] = v.y;
        tile[p * 16 + cy][lx * 4 + 2] = v.z;
        tile[p * 16 + cy][lx * 4 + 3] = v.w;
    }
    __syncthreads();
    const int ocl = t & 15, ot = t >> 4;         // store: 4 bf16 (8B) along C
    unsigned short* xtb = xt + (size_t)b * L * C;
#pragma unroll
    for (int p = 0; p < 4; ++p) {
        int ol = p * 16 + ot;
        union { unsigned short h[4]; uint2 u; } pk;
#pragma unroll
        for (int i = 0; i < 4; ++i) pk.h[i] = f2bf(tile[ocl * 4 + i][ol]);
        *(uint2*)(xtb + (size_t)(l0 + ol) * C + c0 + ocl * 4) = pk.u;
    }
}

// ---------------------------------------------------------------------------
// Kernel 1: QKV projection. 1-D grid 1536: b = id&7 (XCD), r = id>>3:
//   which = r>>6; q/k: m = tt&15 (fastest), n = tt>>4; v: m = tt&3, n = tt>>2
// ---------------------------------------------------------------------------
__global__ __launch_bounds__(256) void qkv_gemm(
    const unsigned short* __restrict__ xt, const unsigned short* __restrict__ Wb,
    const float* __restrict__ bq, const float* __restrict__ bk,
    const float* __restrict__ bv,
    unsigned short* __restrict__ Qt, unsigned short* __restrict__ Kt,
    unsigned short* __restrict__ Vv)
{
    __shared__ unsigned short As[2 * 128 * 32], Bs[2 * 128 * 32];
    const int id = blockIdx.x;
    const int b = id & 7, r = id >> 3;          // r in 0..191
    const int which = r >> 6, tt = r & 63;
    const unsigned short* xtb = xt + (size_t)b * L * C;
    if (which < 2) {
        const int m0 = (tt & 15) * 128, n0 = (tt >> 4) * 128;   // M=L, N=C
        const unsigned short* A  = xtb + (size_t)m0 * C;
        const unsigned short* Bm = Wb + (size_t)which * C * C + (size_t)n0 * C;
        unsigned short* Out = (which ? Kt : Qt) + (size_t)b * L * C
                              + (size_t)m0 * C + n0;
        gemm_core<0, C>(A, Bm, As, Bs, Out, C,
                        const_cast<float*>((which ? bk : bq) + n0));
    } else {
        const int m0 = (tt & 3) * 128, n0 = (tt >> 2) * 128;    // M=C, N=L
        const unsigned short* A  = Wb + (size_t)2 * C * C + (size_t)m0 * C;
        const unsigned short* Bm = xtb + (size_t)n0 * C;
        unsigned short* Out = Vv + (size_t)b * C * L + (size_t)m0 * L + n0;
        gemm_core<1, C>(A, Bm, As, Bs, Out, L, const_cast<float*>(bv + m0));
    }
}

// ---------------------------------------------------------------------------
// Kernel 2: P = exp(Q K^T * scale - 12) + fused row-sum atomics.
// BM=256 x BN=128, BK=64, 512 thr = 8 waves (4M x 2N, per-wave 64x64).
// Single-buffered 48 KiB LDS, 2-barrier K-loop, launch_bounds(512,4)
// (VGPR cap 128, no spill, 2 blocks/CU). Swizzled staging (0 conflicts).
// NEW: coalesced P epilogue — shfl-pack adjacent cols to u32, stage each
// wave's 64x64 tile through its private 4 KiB LDS scratch (As is dead
// after the K-loop), read back b128 rows, store dwordx4 (8 coalesced
// 16-B stores/thread instead of 64 scattered 2-B stores of 67 MB P).
// ---------------------------------------------------------------------------
__global__ __launch_bounds__(512, 4) void sc_exp3(
    const unsigned short* __restrict__ Qt, const unsigned short* __restrict__ Kt,
    unsigned short* __restrict__ P, float* __restrict__ rsum,
    int hoff, int qrows, int mshift)
{
    __shared__ unsigned short As[256 * 64];   // 32 KiB
    __shared__ unsigned short Bs[128 * 64];   // 16 KiB
    constexpr int KD = C;

    const int id = blockIdx.x;
    const int b = id & 7, rr = id >> 3;
    const int m0 = (rr & ((1 << mshift) - 1)) * 256, n0 = (rr >> mshift) * 128;
    const unsigned short* A  = Qt + (size_t)b * L * C + (size_t)(hoff + m0) * C;
    const unsigned short* Bm = Kt + (size_t)b * L * C + (size_t)n0 * C;
    unsigned short* Out = P + (size_t)b * qrows * L + (size_t)m0 * L + n0;
    float* ep = rsum + (size_t)b * L + hoff + m0;

    const int t = threadIdx.x;
    const int wave = t >> 6, lane = t & 63;
    const int ll = t & 15, quad = (t >> 4) & 3;
    const int wm = (wave & 3) * 64, wn = (wave >> 2) * 64;   // 4M x 2N waves

    // staging: thread t covers row r0 = t>>3 (64 rows/call), chunk t&7;
    // fetch global chunk (t&7)^(r0&7)  [inverse swizzle]
    const int r0 = t >> 3;
    const int swz = ((t & 7) ^ (r0 & 7)) * 8;                // elements
    const unsigned short* gA = A  + (size_t)r0 * KD + swz;
    const unsigned short* gB = Bm + (size_t)r0 * KD + swz;
    unsigned short* lA = As + wave * 512;                    // wave-uniform
    unsigned short* lB = Bs + wave * 512;
    const int sw8 = ll & 7;                                  // read-side key

    f32x4 acc[4][4];
#pragma unroll
    for (int i = 0; i < 4; ++i)
#pragma unroll
        for (int j = 0; j < 4; ++j) acc[i][j] = (f32x4){0.f, 0.f, 0.f, 0.f};

#pragma unroll 1
    for (int k0 = 0; k0 < KD; k0 += 64) {
        __syncthreads();                      // prev compute done reading LDS
        load_lds16(gA + k0,                     lA);               // A rows 0-63
        load_lds16(gA + (size_t)64  * KD + k0,  lA + 64 * 64);     // 64-127
        load_lds16(gA + (size_t)128 * KD + k0,  lA + 128 * 64);    // 128-191
        load_lds16(gA + (size_t)192 * KD + k0,  lA + 192 * 64);    // 192-255
        load_lds16(gB + k0,                     lB);               // B rows 0-63
        load_lds16(gB + (size_t)64  * KD + k0,  lB + 64 * 64);     // 64-127
        __syncthreads();                      // staging visible

#pragma unroll
        for (int p = 0; p < 2; ++p) {
            bf16x8 af[4], bf[4];
#pragma unroll
            for (int mi = 0; mi < 4; ++mi)
                af[mi] = *(const bf16x8*)&As[(wm + mi * 16 + ll) * 64
                                             + ((p * 4 + quad) ^ sw8) * 8];
#pragma unroll
            for (int ni = 0; ni < 4; ++ni)
                bf[ni] = *(const bf16x8*)&Bs[(wn + ni * 16 + ll) * 64
                                             + ((p * 4 + quad) ^ sw8) * 8];
#pragma unroll
            for (int mi = 0; mi < 4; ++mi)
#pragma unroll
                for (int ni = 0; ni < 4; ++ni)
                    acc[mi][ni] = MFMA(af[mi], bf[ni], acc[mi][ni]);
        }
    }

    // ---- epilogue: exp2 + rsum; coalesced store via wave-private LDS ----
    __syncthreads();                          // all waves done reading As/Bs
    unsigned* scratch = (unsigned*)As + wave * 1024;   // 4 KiB per wave

    float rpart[4][4];
#pragma unroll
    for (int mi = 0; mi < 4; ++mi)
#pragma unroll
        for (int r = 0; r < 4; ++r) rpart[mi][r] = 0.f;

#pragma unroll
    for (int h = 0; h < 2; ++h) {
        // pack half-tile (32 rows x 64 cols) into scratch as u32 col-pairs
#pragma unroll
        for (int mi2 = 0; mi2 < 2; ++mi2) {
            const int mi = h * 2 + mi2;
#pragma unroll
            for (int ni = 0; ni < 4; ++ni)
#pragma unroll
                for (int r = 0; r < 4; ++r) {
                    float v = exp2f(fmaf(acc[mi][ni][r], SC2, SH2));
                    rpart[mi][r] += v;
                    unsigned bfv = f2bf(v);
                    unsigned pvv = (unsigned)__shfl_xor((int)bfv, 1, 64);
                    unsigned packed = (ll & 1) ? ((pvv & 0xFFFFu) | (bfv << 16))
                                               : ((bfv & 0xFFFFu) | (pvv << 16));
                    if (!(ll & 1))
                        scratch[(mi2 * 16 + quad * 4 + r) * 32 + ni * 8 + (ll >> 1)]
                            = packed;
                }
        }
        // read back 32 rows x 64 cols, store coalesced dwordx4
        // (wave-private region: per-wave LDS ordering, no barrier needed)
#pragma unroll
        for (int i = 0; i < 4; ++i) {
            const int rl = i * 8 + (lane >> 3);
            uint4 d = *(const uint4*)(scratch + rl * 32 + (lane & 7) * 4);
            const int row = wm + h * 32 + rl;
            const int col = wn + (lane & 7) * 8;
            *(uint4*)&Out[(size_t)row * L + col] = d;
        }
    }

#pragma unroll
    for (int mi = 0; mi < 4; ++mi)
#pragma unroll
        for (int r = 0; r < 4; ++r) {
            float s = rpart[mi][r];
            s += __shfl_xor(s, 1, 64);
            s += __shfl_xor(s, 2, 64);
            s += __shfl_xor(s, 4, 64);
            s += __shfl_xor(s, 8, 64);
            if (ll == 0) atomicAdd(ep + wm + mi * 16 + quad * 4 + r, s);
        }
}

// ---------------------------------------------------------------------------
// Kernel 3: O = (V @ P^T) / rsum[col]
// 1-D grid: b = id&7 (XCD), r = id>>3, m = r&3 fastest (M=C: 4 tiles), n rest
// ---------------------------------------------------------------------------
__global__ __launch_bounds__(256) void pv_gemm(
    const unsigned short* __restrict__ Vv, const unsigned short* __restrict__ P,
    const float* __restrict__ rsum, float* __restrict__ out,
    int hoff, int qrows)
{
    __shared__ unsigned short As[2 * 128 * 32], Bs[2 * 128 * 32];
    const int id = blockIdx.x;
    const int b = id & 7, r = id >> 3;
    const int m0 = (r & 3) * 128, n0 = (r >> 2) * 128;
    const unsigned short* A  = Vv + (size_t)b * C * L + (size_t)m0 * L;
    const unsigned short* Bm = P + (size_t)b * qrows * L + (size_t)n0 * L;
    float* Out = out + (size_t)b * C * L + (size_t)m0 * L + hoff + n0;
    float* ep = const_cast<float*>(rsum) + (size_t)b * L + hoff + n0;
    gemm_core<3, L>(A, Bm, As, Bs, Out, L, ep);
}

extern "C" void kernel_launch(void* const* d_in, const int* in_sizes, int n_in,
                              void* d_out, int out_size, void* d_ws, size_t ws_size,
                              hipStream_t stream) {
    const float* x  = (const float*)d_in[0];
    const float* Wq = (const float*)d_in[1];
    const float* bq = (const float*)d_in[2];
    const float* Wk = (const float*)d_in[3];
    const float* bk = (const float*)d_in[4];
    const float* Wv = (const float*)d_in[5];
    const float* bv = (const float*)d_in[6];
    float* out = (float*)d_out;

    const size_t BCL = (size_t)B * C * L;                // 8.39M elems
    const bool fullP = ws_size >= 119078912ull;          // full-P footprint

    unsigned short* Qt = (unsigned short*)d_ws;          // [B][L][C] bf16
    unsigned short* Kt = Qt + BCL;
    unsigned short* Vv = Kt + BCL;                       // [B][C][L]
    unsigned short *Wb, *xt, *P;
    float* rsum;
    if (fullP) {
        Wb   = Vv + BCL;                                 // 1.57 MB, live during qkv
        rsum = (float*)(Wb + (size_t)3 * C * C);         // [B][L] f32
        xt   = (unsigned short*)(rsum + (size_t)B * L);  // dead after qkv
        P    = xt;                                       // [B][L][L] bf16, aliases xt
    } else {                                             // 85.6 MB fallback
        xt   = Vv + BCL;
        P    = xt;                                       // [B][1024][L], aliases xt
        Wb   = P + (size_t)B * 1024 * L;
        rsum = (float*)(Wb + (size_t)3 * C * C);
    }

    prep<<<dim3(L / 64, C / 64, B), 256, 0, stream>>>(x, Wq, Wk, Wv, xt, Wb, rsum);
    qkv_gemm<<<dim3(1536), 256, 0, stream>>>(xt, Wb, bq, bk, bv, Qt, Kt, Vv);

    if (fullP) {
        // 8 m-tiles (256 rows) x 16 n-tiles (128 cols) x 8 b = 1024 blocks
        sc_exp3<<<dim3(1024), 512, 0, stream>>>(Qt, Kt, P, rsum, 0, L, 3);
        pv_gemm<<<dim3(512), 256, 0, stream>>>(Vv, P, rsum, out, 0, L);
    } else {
        for (int h = 0; h < 2; ++h) {
            // 4 m-tiles x 16 n-tiles x 8 b = 512 blocks
            sc_exp3<<<dim3(512), 512, 0, stream>>>(Qt, Kt, P, rsum, h * 1024, 1024, 2);
            pv_gemm<<<dim3(256), 256, 0, stream>>>(Vv, P, rsum, out, h * 1024, 1024);
        }
    }
}

// Round 8
// 221.435 us; speedup vs baseline: 2.0406x; 1.0521x over previous
//
#include <hip/hip_runtime.h>
#include <hip/hip_bf16.h>
#include <math.h>

#define B 8
#define C 512
#define L 2048

using bf16x8 = __bf16 __attribute__((ext_vector_type(8)));
using f32x4  = float __attribute__((ext_vector_type(4)));

#define MFMA(a, b, c) __builtin_amdgcn_mfma_f32_16x16x32_bf16((a), (b), (c), 0, 0, 0)
// exp(v*SCALE - 12) == exp2(v*SC2 + SH2), SCALE = 1/sqrt(512)
#define SC2 0.06375872f
#define SH2 -17.312340f

// RNE f32->bf16 without NaN handling (all values here are finite)
__device__ __forceinline__ unsigned short f2bf(float f) {
    unsigned int u; __builtin_memcpy(&u, &f, 4);
    u += 0x7FFF + ((u >> 16) & 1);
    return (unsigned short)(u >> 16);
}
// async global->LDS, 16B/lane; LDS dest = wave-uniform base + lane*16
__device__ __forceinline__ void load_lds16(const unsigned short* g, unsigned short* l) {
    __builtin_amdgcn_global_load_lds(
        (const __attribute__((address_space(1))) unsigned int*)g,
        (__attribute__((address_space(3))) unsigned int*)l, 16, 0, 0);
}

// ---------------------------------------------------------------------------
// GEMM-NT core (legacy 128x128, 2-barrier): used by qkv_gemm / fallback pv.
// MODE 0: +bias[col], bf16 out      (QKV q/k)
// MODE 1: +bias[row], bf16 out      (QKV v)
// MODE 3: /ep[col], f32 out         (PV, ep = row sums)
// ---------------------------------------------------------------------------
template<int MODE, int KDIM>
__device__ __forceinline__ void gemm_core(
    const unsigned short* __restrict__ A,   // pre-offset to tile row m0
    const unsigned short* __restrict__ Bm,  // pre-offset to tile row n0
    unsigned short* As, unsigned short* Bs, // [2][128*32] each
    void* __restrict__ OutV, int ldo,       // pre-offset to (m0, n0)
    float* __restrict__ ep)                 // bias / rsum (pre-offset)
{
    const int t = threadIdx.x;
    const int wave = t >> 6, lane = t & 63;
    const int ll = t & 15, quad = (t >> 4) & 3;
    const int lr = lane >> 2, chunk = lane & 3;
    const int wm = (wave & 1) * 64, wn = (wave >> 1) * 64;

    const unsigned short* gA0 = A  + (size_t)(wave * 32 + lr) * KDIM + chunk * 8;
    const unsigned short* gB0 = Bm + (size_t)(wave * 32 + lr) * KDIM + chunk * 8;
    unsigned short* lA0 = As + (wave * 32) * 32;        // wave-uniform bases
    unsigned short* lB0 = Bs + (wave * 32) * 32;
    const int P1 = 128 * 32;                            // panel-1 offset

    f32x4 acc[4][4];
#pragma unroll
    for (int i = 0; i < 4; ++i)
#pragma unroll
        for (int j = 0; j < 4; ++j) acc[i][j] = (f32x4){0.f, 0.f, 0.f, 0.f};

#pragma unroll 1
    for (int k0 = 0; k0 < KDIM; k0 += 64) {
        __syncthreads();                      // prev compute done reading LDS
        load_lds16(gA0 + k0, lA0);
        load_lds16(gA0 + (size_t)16 * KDIM + k0, lA0 + 16 * 32);
        load_lds16(gA0 + k0 + 32, lA0 + P1);
        load_lds16(gA0 + (size_t)16 * KDIM + k0 + 32, lA0 + P1 + 16 * 32);
        load_lds16(gB0 + k0, lB0);
        load_lds16(gB0 + (size_t)16 * KDIM + k0, lB0 + 16 * 32);
        load_lds16(gB0 + k0 + 32, lB0 + P1);
        load_lds16(gB0 + (size_t)16 * KDIM + k0 + 32, lB0 + P1 + 16 * 32);
        __syncthreads();                      // staging visible

#pragma unroll
        for (int p = 0; p < 2; ++p) {
            bf16x8 af[4], bf[4];
#pragma unroll
            for (int mi = 0; mi < 4; ++mi)
                af[mi] = *(const bf16x8*)&As[p * P1 + (wm + mi * 16 + ll) * 32 + quad * 8];
#pragma unroll
            for (int ni = 0; ni < 4; ++ni)
                bf[ni] = *(const bf16x8*)&Bs[p * P1 + (wn + ni * 16 + ll) * 32 + quad * 8];
#pragma unroll
            for (int mi = 0; mi < 4; ++mi)
#pragma unroll
                for (int ni = 0; ni < 4; ++ni)
                    acc[mi][ni] = MFMA(af[mi], bf[ni], acc[mi][ni]);
        }
    }

#pragma unroll
    for (int mi = 0; mi < 4; ++mi)
#pragma unroll
        for (int ni = 0; ni < 4; ++ni) {
            const int col = wn + ni * 16 + ll;
            float epc = 0.f;
            if (MODE == 0) epc = ep[col];
            if (MODE == 3) epc = 1.0f / ep[col];
#pragma unroll
            for (int r = 0; r < 4; ++r) {
                const int row = wm + mi * 16 + quad * 4 + r;
                float v = acc[mi][ni][r];
                if (MODE == 0)      v += epc;
                else if (MODE == 1) v += ep[row];
                else                v *= epc;
                if (MODE == 3)
                    ((float*)OutV)[(size_t)row * ldo + col] = v;
                else
                    ((unsigned short*)OutV)[(size_t)row * ldo + col] = f2bf(v);
            }
        }
}

// ---------------------------------------------------------------------------
// Kernel 0 (merged): x transpose/cvt + W cvt + rsum zero. Grid dim3(32,8,8);
// flat block id < 768 additionally does the old wcvt block's work.
// ---------------------------------------------------------------------------
__global__ __launch_bounds__(256) void prep(
    const float* __restrict__ x, const float* __restrict__ Wq,
    const float* __restrict__ Wk, const float* __restrict__ Wv,
    unsigned short* __restrict__ xt, unsigned short* __restrict__ o,
    float* __restrict__ rsum)
{
    __shared__ float tile[64][69];
    const int t = threadIdx.x;
    const int flat = blockIdx.x + 32 * (blockIdx.y + 8 * blockIdx.z);

    if (flat < 768) {               // ---- wcvt part (independent data) ----
        if (flat < 16) {            // zero rsum[B*L] = 16384 floats
            float4 z = make_float4(0.f, 0.f, 0.f, 0.f);
            *(float4*)(rsum + (flat * 256 + t) * 4) = z;
        }
        const int i = (flat * 256 + t) * 4;
        const int which = i >> 18;                            // C*C = 2^18
        const int off = i & 0x3FFFF;
        const float* src = (which == 0) ? Wq : (which == 1) ? Wk : Wv;
        float4 v = *(const float4*)(src + off);
        union { unsigned short h[4]; uint2 u; } pk;
        pk.h[0] = f2bf(v.x); pk.h[1] = f2bf(v.y); pk.h[2] = f2bf(v.z); pk.h[3] = f2bf(v.w);
        *(uint2*)(o + i) = pk.u;
    }

    // ---- xpose part ----
    const int b = blockIdx.z, l0 = blockIdx.x * 64, c0 = blockIdx.y * 64;
    const int lx = t & 15, cy = t >> 4;          // load: float4 along L
    const float* xb = x + (size_t)b * C * L;
#pragma unroll
    for (int p = 0; p < 4; ++p) {
        float4 v = *(const float4*)(xb + (size_t)(c0 + p * 16 + cy) * L + l0 + lx * 4);
        tile[p * 16 + cy][lx * 4 + 0] = v.x;
        tile[p * 16 + cy][lx * 4 + 1] = v.y;
        tile[p * 16 + cy][lx * 4 + 2] = v.z;
        tile[p * 16 + cy][lx * 4 + 3] = v.w;
    }
    __syncthreads();
    const int ocl = t & 15, ot = t >> 4;         // store: 4 bf16 (8B) along C
    unsigned short* xtb = xt + (size_t)b * L * C;
#pragma unroll
    for (int p = 0; p < 4; ++p) {
        int ol = p * 16 + ot;
        union { unsigned short h[4]; uint2 u; } pk;
#pragma unroll
        for (int i = 0; i < 4; ++i) pk.h[i] = f2bf(tile[ocl * 4 + i][ol]);
        *(uint2*)(xtb + (size_t)(l0 + ol) * C + c0 + ocl * 4) = pk.u;
    }
}

// ---------------------------------------------------------------------------
// Kernel 1: QKV projection. 1-D grid 1536: b = id&7 (XCD), r = id>>3:
//   which = r>>6; q/k: m = tt&15 (fastest), n = tt>>4; v: m = tt&3, n = tt>>2
// ---------------------------------------------------------------------------
__global__ __launch_bounds__(256) void qkv_gemm(
    const unsigned short* __restrict__ xt, const unsigned short* __restrict__ Wb,
    const float* __restrict__ bq, const float* __restrict__ bk,
    const float* __restrict__ bv,
    unsigned short* __restrict__ Qt, unsigned short* __restrict__ Kt,
    unsigned short* __restrict__ Vv)
{
    __shared__ unsigned short As[2 * 128 * 32], Bs[2 * 128 * 32];
    const int id = blockIdx.x;
    const int b = id & 7, r = id >> 3;          // r in 0..191
    const int which = r >> 6, tt = r & 63;
    const unsigned short* xtb = xt + (size_t)b * L * C;
    if (which < 2) {
        const int m0 = (tt & 15) * 128, n0 = (tt >> 4) * 128;   // M=L, N=C
        const unsigned short* A  = xtb + (size_t)m0 * C;
        const unsigned short* Bm = Wb + (size_t)which * C * C + (size_t)n0 * C;
        unsigned short* Out = (which ? Kt : Qt) + (size_t)b * L * C
                              + (size_t)m0 * C + n0;
        gemm_core<0, C>(A, Bm, As, Bs, Out, C,
                        const_cast<float*>((which ? bk : bq) + n0));
    } else {
        const int m0 = (tt & 3) * 128, n0 = (tt >> 2) * 128;    // M=C, N=L
        const unsigned short* A  = Wb + (size_t)2 * C * C + (size_t)m0 * C;
        const unsigned short* Bm = xtb + (size_t)n0 * C;
        unsigned short* Out = Vv + (size_t)b * C * L + (size_t)m0 * L + n0;
        gemm_core<1, C>(A, Bm, As, Bs, Out, L, const_cast<float*>(bv + m0));
    }
}

// ---------------------------------------------------------------------------
// Kernel 2: P = exp(Q K^T * scale - 12) + fused row-sum atomics.
// R5-exact (session best): BM=256 x BN=128, BK=64, 512 thr = 8 waves
// (4M x 2N, per-wave 64x64). Single-buffered 48 KiB LDS, 2-barrier K-loop,
// launch_bounds(512,4) (VGPR 56, no spill, 2 blocks/CU). Swizzled staging
// (0 conflicts). Plain scalar P stores — R7 proved L2 write-combines them
// (WRITE_SIZE identical) and the LDS-packed variant regressed 59->73us.
// ---------------------------------------------------------------------------
__global__ __launch_bounds__(512, 4) void sc_exp3(
    const unsigned short* __restrict__ Qt, const unsigned short* __restrict__ Kt,
    unsigned short* __restrict__ P, float* __restrict__ rsum,
    int hoff, int qrows, int mshift)
{
    __shared__ unsigned short As[256 * 64];   // 32 KiB
    __shared__ unsigned short Bs[128 * 64];   // 16 KiB
    constexpr int KD = C;

    const int id = blockIdx.x;
    const int b = id & 7, rr = id >> 3;
    const int m0 = (rr & ((1 << mshift) - 1)) * 256, n0 = (rr >> mshift) * 128;
    const unsigned short* A  = Qt + (size_t)b * L * C + (size_t)(hoff + m0) * C;
    const unsigned short* Bm = Kt + (size_t)b * L * C + (size_t)n0 * C;
    unsigned short* Out = P + (size_t)b * qrows * L + (size_t)m0 * L + n0;
    float* ep = rsum + (size_t)b * L + hoff + m0;

    const int t = threadIdx.x;
    const int wave = t >> 6;
    const int ll = t & 15, quad = (t >> 4) & 3;
    const int wm = (wave & 3) * 64, wn = (wave >> 2) * 64;   // 4M x 2N waves

    const int r0 = t >> 3;
    const int swz = ((t & 7) ^ (r0 & 7)) * 8;                // elements
    const unsigned short* gA = A  + (size_t)r0 * KD + swz;
    const unsigned short* gB = Bm + (size_t)r0 * KD + swz;
    unsigned short* lA = As + wave * 512;                    // wave-uniform
    unsigned short* lB = Bs + wave * 512;
    const int sw8 = ll & 7;                                  // read-side key

    f32x4 acc[4][4];
#pragma unroll
    for (int i = 0; i < 4; ++i)
#pragma unroll
        for (int j = 0; j < 4; ++j) acc[i][j] = (f32x4){0.f, 0.f, 0.f, 0.f};

#pragma unroll 1
    for (int k0 = 0; k0 < KD; k0 += 64) {
        __syncthreads();                      // prev compute done reading LDS
        load_lds16(gA + k0,                     lA);               // A rows 0-63
        load_lds16(gA + (size_t)64  * KD + k0,  lA + 64 * 64);     // 64-127
        load_lds16(gA + (size_t)128 * KD + k0,  lA + 128 * 64);    // 128-191
        load_lds16(gA + (size_t)192 * KD + k0,  lA + 192 * 64);    // 192-255
        load_lds16(gB + k0,                     lB);               // B rows 0-63
        load_lds16(gB + (size_t)64  * KD + k0,  lB + 64 * 64);     // 64-127
        __syncthreads();                      // staging visible

#pragma unroll
        for (int p = 0; p < 2; ++p) {
            bf16x8 af[4], bf[4];
#pragma unroll
            for (int mi = 0; mi < 4; ++mi)
                af[mi] = *(const bf16x8*)&As[(wm + mi * 16 + ll) * 64
                                             + ((p * 4 + quad) ^ sw8) * 8];
#pragma unroll
            for (int ni = 0; ni < 4; ++ni)
                bf[ni] = *(const bf16x8*)&Bs[(wn + ni * 16 + ll) * 64
                                             + ((p * 4 + quad) ^ sw8) * 8];
#pragma unroll
            for (int mi = 0; mi < 4; ++mi)
#pragma unroll
                for (int ni = 0; ni < 4; ++ni)
                    acc[mi][ni] = MFMA(af[mi], bf[ni], acc[mi][ni]);
        }
    }

    // epilogue: exp2, bf16 store, fused row-sum atomics
    float rpart[4][4];
#pragma unroll
    for (int mi = 0; mi < 4; ++mi)
#pragma unroll
        for (int r = 0; r < 4; ++r) rpart[mi][r] = 0.f;

#pragma unroll
    for (int mi = 0; mi < 4; ++mi)
#pragma unroll
        for (int ni = 0; ni < 4; ++ni) {
            const int col = wn + ni * 16 + ll;
#pragma unroll
            for (int r = 0; r < 4; ++r) {
                const int row = wm + mi * 16 + quad * 4 + r;
                float v = exp2f(fmaf(acc[mi][ni][r], SC2, SH2));
                rpart[mi][r] += v;
                Out[(size_t)row * L + col] = f2bf(v);
            }
        }
#pragma unroll
    for (int mi = 0; mi < 4; ++mi)
#pragma unroll
        for (int r = 0; r < 4; ++r) {
            float s = rpart[mi][r];
            s += __shfl_xor(s, 1, 64);
            s += __shfl_xor(s, 2, 64);
            s += __shfl_xor(s, 4, 64);
            s += __shfl_xor(s, 8, 64);
            if (ll == 0) atomicAdd(ep + wm + mi * 16 + quad * 4 + r, s);
        }
}

// ---------------------------------------------------------------------------
// Kernel 3 (NEW): O = (V @ P^T) / rsum[col], 8-wave swizzled core.
// BM=128 (C dim) x BN=256 (P rows), BK=64, K=2048, 512 thr = 8 waves
// (2M x 4N, per-wave 64x64 = acc[4][4], same shape as sc_exp3: ~56 VGPR).
// Staged bytes/output: 1.5 B vs old 128x128 core's 2.0 B; conflicts -> 0
// (same XOR swizzle); 2 blocks/CU. Grid 256: b = id&7, m = r&3, n = r>>2.
// ---------------------------------------------------------------------------
__global__ __launch_bounds__(512, 4) void pv_gemm2(
    const unsigned short* __restrict__ Vv, const unsigned short* __restrict__ P,
    const float* __restrict__ rsum, float* __restrict__ out)
{
    __shared__ unsigned short As[128 * 64];   // 16 KiB (V tile)
    __shared__ unsigned short Bs[256 * 64];   // 32 KiB (P tile)

    const int id = blockIdx.x;
    const int b = id & 7, rr = id >> 3;                  // rr in 0..31
    const int m0 = (rr & 3) * 128, n0 = (rr >> 2) * 256; // 4 m x 8 n
    const unsigned short* A  = Vv + (size_t)b * C * L + (size_t)m0 * L;
    const unsigned short* Bm = P  + (size_t)b * L * L + (size_t)n0 * L;
    float* Out = out + (size_t)b * C * L + (size_t)m0 * L + n0;
    const float* ep = rsum + (size_t)b * L + n0;

    const int t = threadIdx.x;
    const int wave = t >> 6;
    const int ll = t & 15, quad = (t >> 4) & 3;
    const int wm = (wave & 1) * 64, wn = (wave >> 1) * 64;   // 2M x 4N waves

    const int r0 = t >> 3;
    const int swz = ((t & 7) ^ (r0 & 7)) * 8;                // elements
    const unsigned short* gA = A  + (size_t)r0 * L + swz;
    const unsigned short* gB = Bm + (size_t)r0 * L + swz;
    unsigned short* lA = As + wave * 512;                    // wave-uniform
    unsigned short* lB = Bs + wave * 512;
    const int sw8 = ll & 7;

    f32x4 acc[4][4];
#pragma unroll
    for (int i = 0; i < 4; ++i)
#pragma unroll
        for (int j = 0; j < 4; ++j) acc[i][j] = (f32x4){0.f, 0.f, 0.f, 0.f};

#pragma unroll 1
    for (int k0 = 0; k0 < L; k0 += 64) {
        __syncthreads();                      // prev compute done reading LDS
        load_lds16(gA + k0,                    lA);               // V rows 0-63
        load_lds16(gA + (size_t)64  * L + k0,  lA + 64 * 64);     // 64-127
        load_lds16(gB + k0,                    lB);               // P rows 0-63
        load_lds16(gB + (size_t)64  * L + k0,  lB + 64 * 64);     // 64-127
        load_lds16(gB + (size_t)128 * L + k0,  lB + 128 * 64);    // 128-191
        load_lds16(gB + (size_t)192 * L + k0,  lB + 192 * 64);    // 192-255
        __syncthreads();                      // staging visible

#pragma unroll
        for (int p = 0; p < 2; ++p) {
            bf16x8 af[4], bf[4];
#pragma unroll
            for (int mi = 0; mi < 4; ++mi)
                af[mi] = *(const bf16x8*)&As[(wm + mi * 16 + ll) * 64
                                             + ((p * 4 + quad) ^ sw8) * 8];
#pragma unroll
            for (int ni = 0; ni < 4; ++ni)
                bf[ni] = *(const bf16x8*)&Bs[(wn + ni * 16 + ll) * 64
                                             + ((p * 4 + quad) ^ sw8) * 8];
#pragma unroll
            for (int mi = 0; mi < 4; ++mi)
#pragma unroll
                for (int ni = 0; ni < 4; ++ni)
                    acc[mi][ni] = MFMA(af[mi], bf[ni], acc[mi][ni]);
        }
    }

    // epilogue: divide by rsum[col], f32 store
#pragma unroll
    for (int mi = 0; mi < 4; ++mi)
#pragma unroll
        for (int ni = 0; ni < 4; ++ni) {
            const int col = wn + ni * 16 + ll;
            const float inv = 1.0f / ep[col];
#pragma unroll
            for (int r = 0; r < 4; ++r) {
                const int row = wm + mi * 16 + quad * 4 + r;
                Out[(size_t)row * L + col] = acc[mi][ni][r] * inv;
            }
        }
}

// ---------------------------------------------------------------------------
// Fallback pv (ws too small for full P): legacy 128x128 core
// ---------------------------------------------------------------------------
__global__ __launch_bounds__(256) void pv_gemm(
    const unsigned short* __restrict__ Vv, const unsigned short* __restrict__ P,
    const float* __restrict__ rsum, float* __restrict__ out,
    int hoff, int qrows)
{
    __shared__ unsigned short As[2 * 128 * 32], Bs[2 * 128 * 32];
    const int id = blockIdx.x;
    const int b = id & 7, r = id >> 3;
    const int m0 = (r & 3) * 128, n0 = (r >> 2) * 128;
    const unsigned short* A  = Vv + (size_t)b * C * L + (size_t)m0 * L;
    const unsigned short* Bm = P + (size_t)b * qrows * L + (size_t)n0 * L;
    float* Out = out + (size_t)b * C * L + (size_t)m0 * L + hoff + n0;
    float* ep = const_cast<float*>(rsum) + (size_t)b * L + hoff + n0;
    gemm_core<3, L>(A, Bm, As, Bs, Out, L, ep);
}

extern "C" void kernel_launch(void* const* d_in, const int* in_sizes, int n_in,
                              void* d_out, int out_size, void* d_ws, size_t ws_size,
                              hipStream_t stream) {
    const float* x  = (const float*)d_in[0];
    const float* Wq = (const float*)d_in[1];
    const float* bq = (const float*)d_in[2];
    const float* Wk = (const float*)d_in[3];
    const float* bk = (const float*)d_in[4];
    const float* Wv = (const float*)d_in[5];
    const float* bv = (const float*)d_in[6];
    float* out = (float*)d_out;

    const size_t BCL = (size_t)B * C * L;                // 8.39M elems
    const bool fullP = ws_size >= 119078912ull;          // full-P footprint

    unsigned short* Qt = (unsigned short*)d_ws;          // [B][L][C] bf16
    unsigned short* Kt = Qt + BCL;
    unsigned short* Vv = Kt + BCL;                       // [B][C][L]
    unsigned short *Wb, *xt, *P;
    float* rsum;
    if (fullP) {
        Wb   = Vv + BCL;                                 // 1.57 MB, live during qkv
        rsum = (float*)(Wb + (size_t)3 * C * C);         // [B][L] f32
        xt   = (unsigned short*)(rsum + (size_t)B * L);  // dead after qkv
        P    = xt;                                       // [B][L][L] bf16, aliases xt
    } else {                                             // 85.6 MB fallback
        xt   = Vv + BCL;
        P    = xt;                                       // [B][1024][L], aliases xt
        Wb   = P + (size_t)B * 1024 * L;
        rsum = (float*)(Wb + (size_t)3 * C * C);
    }

    prep<<<dim3(L / 64, C / 64, B), 256, 0, stream>>>(x, Wq, Wk, Wv, xt, Wb, rsum);
    qkv_gemm<<<dim3(1536), 256, 0, stream>>>(xt, Wb, bq, bk, bv, Qt, Kt, Vv);

    if (fullP) {
        // sc: 8 m-tiles x 16 n-tiles x 8 b = 1024 blocks
        sc_exp3<<<dim3(1024), 512, 0, stream>>>(Qt, Kt, P, rsum, 0, L, 3);
        // pv2: 4 m-tiles x 8 n-tiles x 8 b = 256 blocks
        pv_gemm2<<<dim3(256), 512, 0, stream>>>(Vv, P, rsum, out);
    } else {
        for (int h = 0; h < 2; ++h) {
            sc_exp3<<<dim3(512), 512, 0, stream>>>(Qt, Kt, P, rsum, h * 1024, 1024, 2);
            pv_gemm<<<dim3(256), 256, 0, stream>>>(Vv, P, rsum, out, h * 1024, 1024);
        }
    }
}

// Round 9
// 212.812 us; speedup vs baseline: 2.1233x; 1.0405x over previous
//
#include <hip/hip_runtime.h>
#include <hip/hip_bf16.h>
#include <math.h>

#define B 8
#define C 512
#define L 2048

using bf16x8 = __bf16 __attribute__((ext_vector_type(8)));
using f32x4  = float __attribute__((ext_vector_type(4)));

#define MFMA(a, b, c) __builtin_amdgcn_mfma_f32_16x16x32_bf16((a), (b), (c), 0, 0, 0)
// exp(v*SCALE - 12) == exp2(v*SC2 + SH2), SCALE = 1/sqrt(512)
#define SC2 0.06375872f
#define SH2 -17.312340f
// rule #18: lgkm wait must be followed by sched_barrier(0) or MFMA hoists past.
#define LGKMC(n) do { asm volatile("s_waitcnt lgkmcnt(" #n ")" ::: "memory"); \
                      __builtin_amdgcn_sched_barrier(0); } while (0)

// RNE f32->bf16 without NaN handling (all values here are finite)
__device__ __forceinline__ unsigned short f2bf(float f) {
    unsigned int u; __builtin_memcpy(&u, &f, 4);
    u += 0x7FFF + ((u >> 16) & 1);
    return (unsigned short)(u >> 16);
}
// async global->LDS, 16B/lane; LDS dest = wave-uniform base + lane*16
__device__ __forceinline__ void load_lds16(const unsigned short* g, unsigned short* l) {
    __builtin_amdgcn_global_load_lds(
        (const __attribute__((address_space(1))) unsigned int*)g,
        (__attribute__((address_space(3))) unsigned int*)l, 16, 0, 0);
}
// inline-asm ds_read_b128: invisible to the waitcnt pass (no conservative
// vmcnt drain vs in-flight LDS-DMA to the other buffer); we order with
// explicit counted lgkmcnt. Proven correct in rounds 2-3.
__device__ __forceinline__ bf16x8 dsr128(unsigned byteoff) {
    bf16x8 r;
    asm volatile("ds_read_b128 %0, %1" : "=v"(r) : "v"(byteoff));
    return r;
}

// ---------------------------------------------------------------------------
// dbuf_gemm128 (NEW, T3-minimum): 128x128 tile, BK=64, 512 thr = 8 waves
// (2M x 4N of 64x32 each), double-buffered 64 KiB LDS -> 2 blocks/CU.
// ONE barrier per K-step, stage-FIRST:
//   STAGE(t+1 -> buf^1)      [4x global_load_lds, async, no wait]
//   12x asm ds_read_b128 from buf[cur]
//   lgkmcnt(6) -> 8 MFMA -> lgkmcnt(0) -> 8 MFMA   [counted, setprio-wrapped]
//   __syncthreads()          [compiler emits vmcnt(0)+lgkmcnt(0) drain HERE:
//                             the stage drain is overlapped with this step's
//                             ds_read+MFMA instead of exposed at issue]
// XOR-swizzled staging/reads as proven (0 bank conflicts): LDS row r holds
// global 16B-chunk c^(r&7) at slot c; frag rows have row&7 == ll&7.
// ---------------------------------------------------------------------------
template<int KDIM>
__device__ __forceinline__ void dbuf_gemm128(
    const unsigned short* __restrict__ gA, int lda,   // pre-offset: +r0*lda+swz
    const unsigned short* __restrict__ gB, int ldb,
    unsigned short* AsBase, unsigned short* BsBase,   // [2][8192] each
    f32x4 (&acc)[4][2])
{
    const int t = threadIdx.x;
    const int wave = t >> 6;
    const int ll = t & 15, quad = (t >> 4) & 3;
    const int wm = (wave & 1) * 64, wn = (wave >> 1) * 32;
    const int sw8 = ll & 7;
    const unsigned c0b = (unsigned)((quad ^ sw8) * 16);
    const unsigned c1b = (unsigned)(((4 + quad) ^ sw8) * 16);
    const unsigned ldsA = (unsigned)(unsigned long long)AsBase;
    const unsigned ldsB = (unsigned)(unsigned long long)BsBase;
    const unsigned aOff = (unsigned)((wm + ll) * 128);   // row base, bytes
    const unsigned bOff = (unsigned)((wn + ll) * 128);
    unsigned short* lA = AsBase + wave * 512;            // wave-uniform dest
    unsigned short* lB = BsBase + wave * 512;
    constexpr int NT = KDIM / 64;

    // prologue: stage tile 0 into buf 0, drain once
    load_lds16(gA,                    lA);
    load_lds16(gA + (size_t)64 * lda, lA + 4096);
    load_lds16(gB,                    lB);
    load_lds16(gB + (size_t)64 * ldb, lB + 4096);
    __syncthreads();

    int cur = 0;
#pragma unroll 1
    for (int kt = 0; kt < NT; ++kt) {
        if (kt + 1 < NT) {                      // stage-first (uniform branch)
            const int k1 = (kt + 1) * 64;
            unsigned short* sA = lA + (cur ^ 1) * 8192;
            unsigned short* sB = lB + (cur ^ 1) * 8192;
            load_lds16(gA + k1,                    sA);
            load_lds16(gA + (size_t)64 * lda + k1, sA + 4096);
            load_lds16(gB + k1,                    sB);
            load_lds16(gB + (size_t)64 * ldb + k1, sB + 4096);
        }
        const unsigned aAdr = ldsA + (unsigned)(cur * 16384) + aOff;
        const unsigned bAdr = ldsB + (unsigned)(cur * 16384) + bOff;
        bf16x8 a0[4], b0[2], a1[4], b1[2];
        // p0 frags first (6), then p1 (6): in-order ds retirement enables
        // the counted lgkmcnt(6) split below.
        a0[0] = dsr128(aAdr + 0 * 2048 + c0b);
        a0[1] = dsr128(aAdr + 1 * 2048 + c0b);
        a0[2] = dsr128(aAdr + 2 * 2048 + c0b);
        a0[3] = dsr128(aAdr + 3 * 2048 + c0b);
        b0[0] = dsr128(bAdr + 0 * 2048 + c0b);
        b0[1] = dsr128(bAdr + 1 * 2048 + c0b);
        a1[0] = dsr128(aAdr + 0 * 2048 + c1b);
        a1[1] = dsr128(aAdr + 1 * 2048 + c1b);
        a1[2] = dsr128(aAdr + 2 * 2048 + c1b);
        a1[3] = dsr128(aAdr + 3 * 2048 + c1b);
        b1[0] = dsr128(bAdr + 0 * 2048 + c1b);
        b1[1] = dsr128(bAdr + 1 * 2048 + c1b);
        LGKMC(6);                               // p0's 6 frags landed
        __builtin_amdgcn_s_setprio(1);
#pragma unroll
        for (int mi = 0; mi < 4; ++mi)
#pragma unroll
            for (int ni = 0; ni < 2; ++ni)
                acc[mi][ni] = MFMA(a0[mi], b0[ni], acc[mi][ni]);
        __builtin_amdgcn_s_setprio(0);
        LGKMC(0);                               // p1's 6 frags landed
        __builtin_amdgcn_s_setprio(1);
#pragma unroll
        for (int mi = 0; mi < 4; ++mi)
#pragma unroll
            for (int ni = 0; ni < 2; ++ni)
                acc[mi][ni] = MFMA(a1[mi], b1[ni], acc[mi][ni]);
        __builtin_amdgcn_s_setprio(0);
        __syncthreads();                        // drains stage(t+1); buf swap
        cur ^= 1;
    }
}

// ---------------------------------------------------------------------------
// GEMM-NT core (legacy 128x128, 2-barrier): used by qkv_gemm (CONTROL) and
// the fallback pv path.
// MODE 0: +bias[col], bf16 out      (QKV q/k)
// MODE 1: +bias[row], bf16 out      (QKV v)
// MODE 3: /ep[col], f32 out         (PV, ep = row sums)
// ---------------------------------------------------------------------------
template<int MODE, int KDIM>
__device__ __forceinline__ void gemm_core(
    const unsigned short* __restrict__ A,   // pre-offset to tile row m0
    const unsigned short* __restrict__ Bm,  // pre-offset to tile row n0
    unsigned short* As, unsigned short* Bs, // [2][128*32] each
    void* __restrict__ OutV, int ldo,       // pre-offset to (m0, n0)
    float* __restrict__ ep)                 // bias / rsum (pre-offset)
{
    const int t = threadIdx.x;
    const int wave = t >> 6, lane = t & 63;
    const int ll = t & 15, quad = (t >> 4) & 3;
    const int lr = lane >> 2, chunk = lane & 3;
    const int wm = (wave & 1) * 64, wn = (wave >> 1) * 64;

    const unsigned short* gA0 = A  + (size_t)(wave * 32 + lr) * KDIM + chunk * 8;
    const unsigned short* gB0 = Bm + (size_t)(wave * 32 + lr) * KDIM + chunk * 8;
    unsigned short* lA0 = As + (wave * 32) * 32;        // wave-uniform bases
    unsigned short* lB0 = Bs + (wave * 32) * 32;
    const int P1 = 128 * 32;                            // panel-1 offset

    f32x4 acc[4][4];
#pragma unroll
    for (int i = 0; i < 4; ++i)
#pragma unroll
        for (int j = 0; j < 4; ++j) acc[i][j] = (f32x4){0.f, 0.f, 0.f, 0.f};

#pragma unroll 1
    for (int k0 = 0; k0 < KDIM; k0 += 64) {
        __syncthreads();                      // prev compute done reading LDS
        load_lds16(gA0 + k0, lA0);
        load_lds16(gA0 + (size_t)16 * KDIM + k0, lA0 + 16 * 32);
        load_lds16(gA0 + k0 + 32, lA0 + P1);
        load_lds16(gA0 + (size_t)16 * KDIM + k0 + 32, lA0 + P1 + 16 * 32);
        load_lds16(gB0 + k0, lB0);
        load_lds16(gB0 + (size_t)16 * KDIM + k0, lB0 + 16 * 32);
        load_lds16(gB0 + k0 + 32, lB0 + P1);
        load_lds16(gB0 + (size_t)16 * KDIM + k0 + 32, lB0 + P1 + 16 * 32);
        __syncthreads();                      // staging visible

#pragma unroll
        for (int p = 0; p < 2; ++p) {
            bf16x8 af[4], bf[4];
#pragma unroll
            for (int mi = 0; mi < 4; ++mi)
                af[mi] = *(const bf16x8*)&As[p * P1 + (wm + mi * 16 + ll) * 32 + quad * 8];
#pragma unroll
            for (int ni = 0; ni < 4; ++ni)
                bf[ni] = *(const bf16x8*)&Bs[p * P1 + (wn + ni * 16 + ll) * 32 + quad * 8];
#pragma unroll
            for (int mi = 0; mi < 4; ++mi)
#pragma unroll
                for (int ni = 0; ni < 4; ++ni)
                    acc[mi][ni] = MFMA(af[mi], bf[ni], acc[mi][ni]);
        }
    }

#pragma unroll
    for (int mi = 0; mi < 4; ++mi)
#pragma unroll
        for (int ni = 0; ni < 4; ++ni) {
            const int col = wn + ni * 16 + ll;
            float epc = 0.f;
            if (MODE == 0) epc = ep[col];
            if (MODE == 3) epc = 1.0f / ep[col];
#pragma unroll
            for (int r = 0; r < 4; ++r) {
                const int row = wm + mi * 16 + quad * 4 + r;
                float v = acc[mi][ni][r];
                if (MODE == 0)      v += epc;
                else if (MODE == 1) v += ep[row];
                else                v *= epc;
                if (MODE == 3)
                    ((float*)OutV)[(size_t)row * ldo + col] = v;
                else
                    ((unsigned short*)OutV)[(size_t)row * ldo + col] = f2bf(v);
            }
        }
}

// ---------------------------------------------------------------------------
// Kernel 0 (merged): x transpose/cvt + W cvt + rsum zero. Grid dim3(32,8,8);
// flat block id < 768 additionally does the old wcvt block's work.
// ---------------------------------------------------------------------------
__global__ __launch_bounds__(256) void prep(
    const float* __restrict__ x, const float* __restrict__ Wq,
    const float* __restrict__ Wk, const float* __restrict__ Wv,
    unsigned short* __restrict__ xt, unsigned short* __restrict__ o,
    float* __restrict__ rsum)
{
    __shared__ float tile[64][69];
    const int t = threadIdx.x;
    const int flat = blockIdx.x + 32 * (blockIdx.y + 8 * blockIdx.z);

    if (flat < 768) {               // ---- wcvt part (independent data) ----
        if (flat < 16) {            // zero rsum[B*L] = 16384 floats
            float4 z = make_float4(0.f, 0.f, 0.f, 0.f);
            *(float4*)(rsum + (flat * 256 + t) * 4) = z;
        }
        const int i = (flat * 256 + t) * 4;
        const int which = i >> 18;                            // C*C = 2^18
        const int off = i & 0x3FFFF;
        const float* src = (which == 0) ? Wq : (which == 1) ? Wk : Wv;
        float4 v = *(const float4*)(src + off);
        union { unsigned short h[4]; uint2 u; } pk;
        pk.h[0] = f2bf(v.x); pk.h[1] = f2bf(v.y); pk.h[2] = f2bf(v.z); pk.h[3] = f2bf(v.w);
        *(uint2*)(o + i) = pk.u;
    }

    // ---- xpose part ----
    const int b = blockIdx.z, l0 = blockIdx.x * 64, c0 = blockIdx.y * 64;
    const int lx = t & 15, cy = t >> 4;          // load: float4 along L
    const float* xb = x + (size_t)b * C * L;
#pragma unroll
    for (int p = 0; p < 4; ++p) {
        float4 v = *(const float4*)(xb + (size_t)(c0 + p * 16 + cy) * L + l0 + lx * 4);
        tile[p * 16 + cy][lx * 4 + 0] = v.x;
        tile[p * 16 + cy][lx * 4 + 1] = v.y;
        tile[p * 16 + cy][lx * 4 + 2] = v.z;
        tile[p * 16 + cy][lx * 4 + 3] = v.w;
    }
    __syncthreads();
    const int ocl = t & 15, ot = t >> 4;         // store: 4 bf16 (8B) along C
    unsigned short* xtb = xt + (size_t)b * L * C;
#pragma unroll
    for (int p = 0; p < 4; ++p) {
        int ol = p * 16 + ot;
        union { unsigned short h[4]; uint2 u; } pk;
#pragma unroll
        for (int i = 0; i < 4; ++i) pk.h[i] = f2bf(tile[ocl * 4 + i][ol]);
        *(uint2*)(xtb + (size_t)(l0 + ol) * C + c0 + ocl * 4) = pk.u;
    }
}

// ---------------------------------------------------------------------------
// Kernel 1 (CONTROL, unchanged): QKV projection, legacy core. 1-D grid 1536.
// ---------------------------------------------------------------------------
__global__ __launch_bounds__(256) void qkv_gemm(
    const unsigned short* __restrict__ xt, const unsigned short* __restrict__ Wb,
    const float* __restrict__ bq, const float* __restrict__ bk,
    const float* __restrict__ bv,
    unsigned short* __restrict__ Qt, unsigned short* __restrict__ Kt,
    unsigned short* __restrict__ Vv)
{
    __shared__ unsigned short As[2 * 128 * 32], Bs[2 * 128 * 32];
    const int id = blockIdx.x;
    const int b = id & 7, r = id >> 3;          // r in 0..191
    const int which = r >> 6, tt = r & 63;
    const unsigned short* xtb = xt + (size_t)b * L * C;
    if (which < 2) {
        const int m0 = (tt & 15) * 128, n0 = (tt >> 4) * 128;   // M=L, N=C
        const unsigned short* A  = xtb + (size_t)m0 * C;
        const unsigned short* Bm = Wb + (size_t)which * C * C + (size_t)n0 * C;
        unsigned short* Out = (which ? Kt : Qt) + (size_t)b * L * C
                              + (size_t)m0 * C + n0;
        gemm_core<0, C>(A, Bm, As, Bs, Out, C,
                        const_cast<float*>((which ? bk : bq) + n0));
    } else {
        const int m0 = (tt & 3) * 128, n0 = (tt >> 2) * 128;    // M=C, N=L
        const unsigned short* A  = Wb + (size_t)2 * C * C + (size_t)m0 * C;
        const unsigned short* Bm = xtb + (size_t)n0 * C;
        unsigned short* Out = Vv + (size_t)b * C * L + (size_t)m0 * L + n0;
        gemm_core<1, C>(A, Bm, As, Bs, Out, L, const_cast<float*>(bv + m0));
    }
}

// ---------------------------------------------------------------------------
// Kernel 2 (NEW core): P = exp(Q K^T * scale - 12) + fused row-sum atomics.
// 128x128 tile on dbuf_gemm128. Grid: b = id&7 (XCD), rr = id>>3,
// m = rr & ((1<<mshift)-1) fastest (shares K-panel), n = rr >> mshift.
// ---------------------------------------------------------------------------
__global__ __launch_bounds__(512, 4) void sc_exp4(
    const unsigned short* __restrict__ Qt, const unsigned short* __restrict__ Kt,
    unsigned short* __restrict__ P, float* __restrict__ rsum,
    int hoff, int qrows, int mshift)
{
    __shared__ unsigned short As[2][8192], Bs[2][8192];   // 64 KiB
    const int id = blockIdx.x;
    const int b = id & 7, rr = id >> 3;
    const int m0 = (rr & ((1 << mshift) - 1)) * 128, n0 = (rr >> mshift) * 128;

    const int t = threadIdx.x;
    const int r0 = t >> 3;
    const int swz = ((t & 7) ^ (r0 & 7)) * 8;            // inverse swizzle
    const unsigned short* gA = Qt + (size_t)b * L * C
                               + (size_t)(hoff + m0 + r0) * C + swz;
    const unsigned short* gB = Kt + (size_t)b * L * C
                               + (size_t)(n0 + r0) * C + swz;

    f32x4 acc[4][2];
#pragma unroll
    for (int i = 0; i < 4; ++i)
#pragma unroll
        for (int j = 0; j < 2; ++j) acc[i][j] = (f32x4){0.f, 0.f, 0.f, 0.f};

    dbuf_gemm128<C>(gA, C, gB, C, &As[0][0], &Bs[0][0], acc);

    // epilogue: exp2, bf16 store, fused row-sum atomics
    unsigned short* Out = P + (size_t)b * qrows * L + (size_t)m0 * L + n0;
    float* ep = rsum + (size_t)b * L + hoff + m0;
    const int wave = t >> 6;
    const int ll = t & 15, quad = (t >> 4) & 3;
    const int wm = (wave & 1) * 64, wn = (wave >> 1) * 32;

    float rpart[4][4];
#pragma unroll
    for (int mi = 0; mi < 4; ++mi)
#pragma unroll
        for (int r = 0; r < 4; ++r) rpart[mi][r] = 0.f;

#pragma unroll
    for (int mi = 0; mi < 4; ++mi)
#pragma unroll
        for (int ni = 0; ni < 2; ++ni) {
            const int col = wn + ni * 16 + ll;
#pragma unroll
            for (int r = 0; r < 4; ++r) {
                const int row = wm + mi * 16 + quad * 4 + r;
                float v = exp2f(fmaf(acc[mi][ni][r], SC2, SH2));
                rpart[mi][r] += v;
                Out[(size_t)row * L + col] = f2bf(v);
            }
        }
#pragma unroll
    for (int mi = 0; mi < 4; ++mi)
#pragma unroll
        for (int r = 0; r < 4; ++r) {
            float s = rpart[mi][r];
            s += __shfl_xor(s, 1, 64);
            s += __shfl_xor(s, 2, 64);
            s += __shfl_xor(s, 4, 64);
            s += __shfl_xor(s, 8, 64);
            if (ll == 0) atomicAdd(ep + wm + mi * 16 + quad * 4 + r, s);
        }
}

// ---------------------------------------------------------------------------
// Kernel 3 (NEW core): O = (V @ P^T) / rsum[col]. 128x128 on dbuf_gemm128,
// K = L = 2048. Grid 512: b = id&7, rr = id>>3, m = rr&3, n = rr>>2.
// ---------------------------------------------------------------------------
__global__ __launch_bounds__(512, 4) void pv_gemm3(
    const unsigned short* __restrict__ Vv, const unsigned short* __restrict__ P,
    const float* __restrict__ rsum, float* __restrict__ out)
{
    __shared__ unsigned short As[2][8192], Bs[2][8192];   // 64 KiB
    const int id = blockIdx.x;
    const int b = id & 7, rr = id >> 3;                   // rr in 0..63
    const int m0 = (rr & 3) * 128, n0 = (rr >> 2) * 128;  // 4 m x 16 n

    const int t = threadIdx.x;
    const int r0 = t >> 3;
    const int swz = ((t & 7) ^ (r0 & 7)) * 8;
    const unsigned short* gA = Vv + (size_t)b * C * L
                               + (size_t)(m0 + r0) * L + swz;
    const unsigned short* gB = P + (size_t)b * L * L
                               + (size_t)(n0 + r0) * L + swz;

    f32x4 acc[4][2];
#pragma unroll
    for (int i = 0; i < 4; ++i)
#pragma unroll
        for (int j = 0; j < 2; ++j) acc[i][j] = (f32x4){0.f, 0.f, 0.f, 0.f};

    dbuf_gemm128<L>(gA, L, gB, L, &As[0][0], &Bs[0][0], acc);

    // epilogue: divide by rsum[col], f32 store
    float* Out = out + (size_t)b * C * L + (size_t)m0 * L + n0;
    const float* ep = rsum + (size_t)b * L + n0;
    const int wave = t >> 6;
    const int ll = t & 15, quad = (t >> 4) & 3;
    const int wm = (wave & 1) * 64, wn = (wave >> 1) * 32;

#pragma unroll
    for (int mi = 0; mi < 4; ++mi)
#pragma unroll
        for (int ni = 0; ni < 2; ++ni) {
            const int col = wn + ni * 16 + ll;
            const float inv = 1.0f / ep[col];
#pragma unroll
            for (int r = 0; r < 4; ++r) {
                const int row = wm + mi * 16 + quad * 4 + r;
                Out[(size_t)row * L + col] = acc[mi][ni][r] * inv;
            }
        }
}

// ---------------------------------------------------------------------------
// Fallback pv (ws too small for full P): legacy 128x128 core
// ---------------------------------------------------------------------------
__global__ __launch_bounds__(256) void pv_gemm(
    const unsigned short* __restrict__ Vv, const unsigned short* __restrict__ P,
    const float* __restrict__ rsum, float* __restrict__ out,
    int hoff, int qrows)
{
    __shared__ unsigned short As[2 * 128 * 32], Bs[2 * 128 * 32];
    const int id = blockIdx.x;
    const int b = id & 7, r = id >> 3;
    const int m0 = (r & 3) * 128, n0 = (r >> 2) * 128;
    const unsigned short* A  = Vv + (size_t)b * C * L + (size_t)m0 * L;
    const unsigned short* Bm = P + (size_t)b * qrows * L + (size_t)n0 * L;
    float* Out = out + (size_t)b * C * L + (size_t)m0 * L + hoff + n0;
    float* ep = const_cast<float*>(rsum) + (size_t)b * L + hoff + n0;
    gemm_core<3, L>(A, Bm, As, Bs, Out, L, ep);
}

extern "C" void kernel_launch(void* const* d_in, const int* in_sizes, int n_in,
                              void* d_out, int out_size, void* d_ws, size_t ws_size,
                              hipStream_t stream) {
    const float* x  = (const float*)d_in[0];
    const float* Wq = (const float*)d_in[1];
    const float* bq = (const float*)d_in[2];
    const float* Wk = (const float*)d_in[3];
    const float* bk = (const float*)d_in[4];
    const float* Wv = (const float*)d_in[5];
    const float* bv = (const float*)d_in[6];
    float* out = (float*)d_out;

    const size_t BCL = (size_t)B * C * L;                // 8.39M elems
    const bool fullP = ws_size >= 119078912ull;          // full-P footprint

    unsigned short* Qt = (unsigned short*)d_ws;          // [B][L][C] bf16
    unsigned short* Kt = Qt + BCL;
    unsigned short* Vv = Kt + BCL;                       // [B][C][L]
    unsigned short *Wb, *xt, *P;
    float* rsum;
    if (fullP) {
        Wb   = Vv + BCL;                                 // 1.57 MB, live during qkv
        rsum = (float*)(Wb + (size_t)3 * C * C);         // [B][L] f32
        xt   = (unsigned short*)(rsum + (size_t)B * L);  // dead after qkv
        P    = xt;                                       // [B][L][L] bf16, aliases xt
    } else {                                             // 85.6 MB fallback
        xt   = Vv + BCL;
        P    = xt;                                       // [B][1024][L], aliases xt
        Wb   = P + (size_t)B * 1024 * L;
        rsum = (float*)(Wb + (size_t)3 * C * C);
    }

    prep<<<dim3(L / 64, C / 64, B), 256, 0, stream>>>(x, Wq, Wk, Wv, xt, Wb, rsum);
    qkv_gemm<<<dim3(1536), 256, 0, stream>>>(xt, Wb, bq, bk, bv, Qt, Kt, Vv);

    if (fullP) {
        // sc: 16 m x 16 n x 8 b = 2048 blocks (mshift=4)
        sc_exp4<<<dim3(2048), 512, 0, stream>>>(Qt, Kt, P, rsum, 0, L, 4);
        // pv: 4 m x 16 n x 8 b = 512 blocks
        pv_gemm3<<<dim3(512), 512, 0, stream>>>(Vv, P, rsum, out);
    } else {
        for (int h = 0; h < 2; ++h) {
            // sc: 8 m x 16 n x 8 b = 1024 blocks (mshift=3)
            sc_exp4<<<dim3(1024), 512, 0, stream>>>(Qt, Kt, P, rsum, h * 1024, 1024, 3);
            pv_gemm<<<dim3(256), 256, 0, stream>>>(Vv, P, rsum, out, h * 1024, 1024);
        }
    }
}